// Round 10
// baseline (301.688 us; speedup 1.0000x reference)
//
#include <hip/hip_runtime.h>
#include <hip/hip_bf16.h>

// Problem constants
#define BATCH 16
#define IN_C 3
#define Q_C 8
#define V_C 16
#define HH 224
#define WW 224
#define KK 7

// Padded layouts
#define XPH 230   // plane row = orig x row + 3
#define QPH 118
#define QPW 120

// Region sizes (elements)
#define PLANES_N (BATCH*7*IN_C*XPH*QPW)        // 9,273,600 bf16
#define VPAD_N   (BATCH*V_C*QPH*QPW)           // 3,624,960 f32
#define QPAD1_STRIDE (Q_C*QPH*QPW)             // 113,280 per (b,ic)
#define QPAD1_N  (BATCH*IN_C*QPAD1_STRIDE)     // 5,437,440 bf16 (single copy!)
#define D_N      (BATCH*IN_C*128*160)          // 983,040 f32
#define OUT_N    (BATCH*IN_C*58*58)

#define PSTR 137                               // ring plane stride in uint4 (8*17+1: banks +4 mod 32)
#define ONES_BASE (21*PSTR)

typedef __attribute__((ext_vector_type(8))) short bf16x8;
typedef __attribute__((ext_vector_type(4))) float f32x4;

static __device__ inline unsigned short f2b(float f) {
    __hip_bfloat16 h = __float2bfloat16(f);
    return *reinterpret_cast<unsigned short*>(&h);
}

// ---------------- Kernel X: dx-deinterleaved bf16 planes of x ----------------
__global__ __launch_bounds__(256) void kX(const float* __restrict__ x,
                                          unsigned short* __restrict__ planes) {
    int idx = blockIdx.x * 256 + threadIdx.x;
    if (idx >= PLANES_N) return;
    int k = idx % QPW;
    int t = idx / QPW;
    int row = t % XPH; t /= XPH;
    int ci = t % IN_C; t /= IN_C;
    int dx = t % 7;
    int b  = t / 7;
    int r = row - 3;
    int c = 2 * k + dx - 3;
    float val = 0.0f;
    if (r >= 0 && r < HH && c >= 0 && c < WW)
        val = x[((size_t)(b * IN_C + ci) * HH + r) * WW + c];
    planes[idx] = f2b(val);
}

// ---------------- Kernel QV: q conv (-> single-copy qpad bf16) + v conv ------
__global__ __launch_bounds__(256) void kQV(const unsigned short* __restrict__ planes,
                                           const float* __restrict__ Wq,
                                           const float* __restrict__ bq,
                                           const float* __restrict__ Wv,
                                           const float* __restrict__ bv,
                                           unsigned short* __restrict__ qpad,
                                           float* __restrict__ vpad) {
    int blk = blockIdx.x;               // b*70 + pb*10 + grp
    int grp = blk % 10;
    int t2  = blk / 10;
    int pb  = t2 % 7;
    int b   = t2 / 7;
    int tid = threadIdx.x;

    __shared__ float wlds[4 * IN_C * KK * 8];   // [cc][ci][dy][dx pad 8]
    __shared__ float bsh[4];

    if (tid < 84) {
        int cc = tid / 21, rest = tid % 21;
        int ch = 4 * grp + cc;
        const float* wsrc = (ch < 24) ? (Wq + (size_t)ch * 147)
                                      : (Wv + (size_t)(ch - 24) * 147);
        #pragma unroll
        for (int dx = 0; dx < 7; ++dx) wlds[tid * 8 + dx] = wsrc[rest * 7 + dx];
        wlds[tid * 8 + 7] = 0.0f;
    }
    if (tid < 4) {
        int ch = 4 * grp + tid;
        bsh[tid] = (ch < 24) ? bq[ch] : bv[ch - 24];
    }
    __syncthreads();

    int pos = pb * 256 + tid;
    if (pos >= 112 * 14) return;
    int y   = pos / 14;
    int seg = pos - y * 14;

    float kv[4][8];
    #pragma unroll
    for (int cc = 0; cc < 4; ++cc)
        #pragma unroll
        for (int j = 0; j < 8; ++j) kv[cc][j] = bsh[cc];

    for (int ci = 0; ci < IN_C; ++ci) {
        for (int dy = 0; dy < KK; ++dy) {
            int absrow = 2 * y + dy;
            float wv_[4][8];
            #pragma unroll
            for (int cc = 0; cc < 4; ++cc) {
                const float* wbase = &wlds[((cc * IN_C + ci) * KK + dy) * 8];
                *(float4*)&wv_[cc][0] = ((const float4*)wbase)[0];
                *(float4*)&wv_[cc][4] = ((const float4*)wbase)[1];
            }
            #pragma unroll
            for (int dx = 0; dx < 7; ++dx) {
                const unsigned short* src = planes
                    + (((size_t)(b * 7 + dx) * IN_C + ci) * XPH + absrow) * QPW + 8 * seg;
                uint4 rv = *(const uint4*)src;
                float xf[8];
                xf[0] = __uint_as_float(rv.x << 16);
                xf[1] = __uint_as_float(rv.x & 0xFFFF0000u);
                xf[2] = __uint_as_float(rv.y << 16);
                xf[3] = __uint_as_float(rv.y & 0xFFFF0000u);
                xf[4] = __uint_as_float(rv.z << 16);
                xf[5] = __uint_as_float(rv.z & 0xFFFF0000u);
                xf[6] = __uint_as_float(rv.w << 16);
                xf[7] = __uint_as_float(rv.w & 0xFFFF0000u);
                #pragma unroll
                for (int cc = 0; cc < 4; ++cc)
                    #pragma unroll
                    for (int j = 0; j < 8; ++j)
                        kv[cc][j] = fmaf(wv_[cc][dx], xf[j], kv[cc][j]);
            }
        }
    }

    int row = y + 3, c0 = 8 * seg + 3;
    if (grp < 6) {
        // single copy: qpad[(b,ic)][qc][row][e], e = orig col + 3
        #pragma unroll
        for (int cc = 0; cc < 4; ++cc) {
            int ch = 4 * grp + cc;
            int icq = ch >> 3, qc = ch & 7;
            unsigned short* bp = qpad
                + ((size_t)(b * IN_C + icq) * Q_C + qc) * (QPH * QPW)
                + (size_t)row * QPW + c0;
            bp[0] = f2b(kv[cc][0]);
            unsigned int* dp = (unsigned int*)(bp + 1);   // byte offset 16seg+8: dword-aligned
            dp[0] = (unsigned int)f2b(kv[cc][1]) | ((unsigned int)f2b(kv[cc][2]) << 16);
            dp[1] = (unsigned int)f2b(kv[cc][3]) | ((unsigned int)f2b(kv[cc][4]) << 16);
            dp[2] = (unsigned int)f2b(kv[cc][5]) | ((unsigned int)f2b(kv[cc][6]) << 16);
            bp[7] = f2b(kv[cc][7]);
        }
    } else {
        #pragma unroll
        for (int cc = 0; cc < 4; ++cc) {
            int vc = 4 * grp + cc - 24;
            float* op = vpad + (((size_t)(b * V_C + vc)) * QPH + row) * QPW + c0;
            #pragma unroll
            for (int j = 0; j < 8; ++j) op[j] = kv[cc][j];
        }
    }
}

// ---------------- Kernel C: MFMA GEMM, ring-buffer B + single-copy A ---------
// Block = (b, yc). 512 thr / 8 waves, M=384 shared-B. A fragments come from
// the single qpad copy: lane's tw shift = 2 elements = 1 dword, realized as
// two aligned uint4 loads + dword selects (VALU idle anyway).
// Ring plane stride PSTR=137 uint4 (+4 banks mod 32: <=2-way conflicts, free).
// R9 bug fixed here: ones row K-tail (chunks 14..16, k>=112) must be ZERO —
// R9 wrote 1.0 through k=127, contaminating D[.,147] (bias path) with
// clamped-A garbage -> absmax 5.8e6.
__global__ __launch_bounds__(512, 1) void kC(const unsigned short* __restrict__ planes,
                                             const unsigned short* __restrict__ qpad,
                                             float* __restrict__ D) {
    int blk = blockIdx.x;
    int b  = blk & 15;
    int yc = blk >> 4;
    int tid = threadIdx.x;
    int w = tid >> 6, lane = tid & 63;
    int tt = lane & 15, kq = lane >> 4;
    int th = tt >> 2, tw = tt & 3;
    bool t1 = (tw & 1) != 0, t2 = (tw & 2) != 0;

    __shared__ uint4 smem[21 * PSTR + 17];   // 21 planes x (8-slot ring x 17) + ones

    // zero k-pad chunks 14,15 of every (plane,slot) row  [PSTR-correct]
    if (tid < 336) {
        int r = tid >> 1;                 // 0..167 = plane*8 + slot
        int p = r >> 3, slot = r & 7;
        smem[p * PSTR + slot * 17 + 14 + (tid & 1)] = uint4{0, 0, 0, 0};
    }
    // ones row: 1.0 for k<112 (chunks 0..13), 0 for the K-tail (chunks 14..16)
    if (tid >= 495) {
        int c = tid - 495;                // 0..16
        unsigned vv = (c < 14) ? 0x3F803F80u : 0u;
        uint4 o; o.x = o.y = o.z = o.w = vv;
        smem[ONES_BASE + c] = o;
    }
    // initial stage: slots 0..6 = plane rows 16*yc .. 16*yc+6
    #pragma unroll
    for (int i = 0; i < 5; ++i) {
        int c = tid + 512 * i;
        if (c < 21 * 7 * 14) {
            int p   = c / 98;
            int rem = c % 98;
            int rr  = rem / 14;
            int kc  = rem % 14;
            int ci = p / 7, dx = p % 7;
            const unsigned short* src = planes
                + (((size_t)(b * 7 + dx) * IN_C + ci) * XPH + 16 * yc + rr) * QPW + kc * 8;
            smem[p * PSTR + rr * 17 + kc] = *(const uint4*)src;
        }
    }

    // per-lane B-fragment LDS addressing constants
    int nbase[10], ndy[10], nmsk[10];
    #pragma unroll
    for (int nt = 0; nt < 10; ++nt) {
        int n = nt * 16 + tt;
        if (n < 147) {
            int ci = n / 49, rr = n % 49;
            nbase[nt] = (ci * 7 + (rr % 7)) * PSTR;
            ndy[nt]   = rr / 7;
            nmsk[nt]  = 7;
        } else {
            nbase[nt] = ONES_BASE; ndy[nt] = 0; nmsk[nt] = 0;
        }
    }

    // A row base per tile j: qpad[(b,ic)][qc] row (2*th)
    const unsigned short* abase[3];
    #pragma unroll
    for (int j = 0; j < 3; ++j) {
        int tile = w * 3 + j;
        int ic = tile >> 3, qc = tile & 7;
        abase[j] = qpad + ((size_t)(b * IN_C + ic) * Q_C + qc) * (QPH * QPW)
                 + (size_t)(2 * th) * QPW;
    }

    f32x4 acc[3][10];
    #pragma unroll
    for (int j = 0; j < 3; ++j)
        #pragma unroll
        for (int nt = 0; nt < 10; ++nt)
            acc[j][nt] = f32x4{0.f, 0.f, 0.f, 0.f};

    __syncthreads();

    for (int ry = 0; ry < 8; ++ry) {
        int yo = yc * 8 + ry;
        // prefetch next two plane rows (2*yo+7, 2*yo+8) into registers
        uint4 pv0, pv1; int pd0 = -1, pd1 = -1;
        if (ry < 7) {
            {
                int c = tid;
                int rn = c / 294, rem = c % 294;
                int p = rem / 14, kc = rem % 14;
                int ci = p / 7, dx = p % 7;
                int absrow = 16 * yc + 2 * ry + 7 + rn;
                pv0 = *(const uint4*)(planes
                    + (((size_t)(b * 7 + dx) * IN_C + ci) * XPH + absrow) * QPW + kc * 8);
                pd0 = p * PSTR + (absrow & 7) * 17 + kc;
            }
            int c = tid + 512;
            if (c < 588) {
                int rn = c / 294, rem = c % 294;
                int p = rem / 14, kc = rem % 14;
                int ci = p / 7, dx = p % 7;
                int absrow = 16 * yc + 2 * ry + 7 + rn;
                pv1 = *(const uint4*)(planes
                    + (((size_t)(b * 7 + dx) * IN_C + ci) * XPH + absrow) * QPW + kc * 8);
                pd1 = p * PSTR + (absrow & 7) * 17 + kc;
            }
        }
        int ry2 = 2 * ry;
        #pragma unroll
        for (int s = 0; s < 4; ++s) {
            int k = 32 * s + kq * 8;
            int xs = (k < 112) ? k : 96;       // clamped; multiplies B-zeros
            bf16x8 af[3];
            #pragma unroll
            for (int j = 0; j < 3; ++j) {
                const unsigned int* dp =
                    (const unsigned int*)(abase[j] + (size_t)yo * QPW) + (xs >> 1);
                uint4 U0 = *(const uint4*)dp;
                uint4 U1 = *(const uint4*)(dp + 4);
                // fragment dword r = X[tw + r], X = concat(U0,U1)
                unsigned int f0 = t2 ? (t1 ? U0.w : U0.z) : (t1 ? U0.y : U0.x);
                unsigned int f1 = t2 ? (t1 ? U1.x : U0.w) : (t1 ? U0.z : U0.y);
                unsigned int f2 = t2 ? (t1 ? U1.y : U1.x) : (t1 ? U0.w : U0.z);
                unsigned int f3 = t2 ? (t1 ? U1.z : U1.y) : (t1 ? U1.x : U0.w);
                uint4 fr{f0, f1, f2, f3};
                af[j] = __builtin_bit_cast(bf16x8, fr);
            }
            #pragma unroll
            for (int nt = 0; nt < 10; ++nt) {
                bf16x8 bf = __builtin_bit_cast(bf16x8,
                    smem[nbase[nt] + ((ry2 + ndy[nt]) & nmsk[nt]) * 17 + 4 * s + kq]);
                #pragma unroll
                for (int j = 0; j < 3; ++j)
                    acc[j][nt] = __builtin_amdgcn_mfma_f32_16x16x32_bf16(af[j], bf, acc[j][nt], 0, 0, 0);
            }
        }
        __syncthreads();                        // all reads of ring done
        if (pd0 >= 0) smem[pd0] = pv0;
        if (pd1 >= 0) smem[pd1] = pv1;
        __syncthreads();                        // new rows visible
    }

    // epilogue: atomics into D. C/D layout: col = lane&15, row = (lane>>4)*4+reg
    int rowb = kq * 4;
    #pragma unroll
    for (int j = 0; j < 3; ++j) {
        int tile = w * 3 + j;
        int ic = tile >> 3, qc = tile & 7;
        float* Dbi = D + (size_t)(b * IN_C + ic) * (128 * 160);
        int m = qc * 16 + rowb;
        #pragma unroll
        for (int nt = 0; nt < 10; ++nt) {
            int n = nt * 16 + tt;
            if (n < 148) {
                #pragma unroll
                for (int r = 0; r < 4; ++r)
                    atomicAdd(&Dbi[(size_t)(m + r) * 160 + n], acc[j][nt][r]);
            }
        }
    }
}

// ---------------- Kernel E: a[v,t] = sum_{qc,r} Wk*D + sum_qc bk*D[.,147] ----
__global__ __launch_bounds__(256) void kE(const float* __restrict__ D,
                                          const float* __restrict__ Wk,
                                          const float* __restrict__ bk,
                                          float* __restrict__ a_out) {
    int blk = blockIdx.x;              // (b*3+ic)*16 + v
    int bi = blk >> 4;
    int v  = blk & 15;
    int ic = bi % IN_C;
    int tid = threadIdx.x;
    int t  = tid >> 4;
    int rl = tid & 15;
    const float* Dbi = D + (size_t)bi * (128 * 160);
    const float* WkI = Wk + (size_t)(ic * V_C + v) * (Q_C * 147);
    const float* bkI = bk + (ic * V_C + v) * Q_C;
    float s = 0.0f;
    for (int qc = 0; qc < Q_C; ++qc) {
        const float* drow = Dbi + (qc * 16 + t) * 160;
        const float* wrow = WkI + qc * 147;
        #pragma unroll
        for (int j = 0; j < 10; ++j) {
            int r = rl + 16 * j;
            if (r < 147) s = fmaf(wrow[r], drow[r], s);
        }
        if (rl == 0) s = fmaf(bkI[qc], drow[147], s);
    }
    s += __shfl_down(s, 8, 64);
    s += __shfl_down(s, 4, 64);
    s += __shfl_down(s, 2, 64);
    s += __shfl_down(s, 1, 64);
    if (rl == 0) a_out[(size_t)blk * 16 + t] = s;
}

// ---------------- Kernel O: final dynamic conv -> out ----------------
__global__ __launch_bounds__(256) void kO(const float* __restrict__ vpad,
                                          const float* __restrict__ a,
                                          float* __restrict__ out) {
    int idx = blockIdx.x * 256 + threadIdx.x;
    if (idx >= OUT_N) return;
    int ow = idx % 58;
    int t = idx / 58;
    int oh = t % 58; t /= 58;
    int ic = t % IN_C;
    int b  = t / IN_C;
    const float* ab = a + (size_t)(b * IN_C + ic) * (V_C * 16);
    float s = 0.0f;
    for (int vc = 0; vc < V_C; ++vc) {
        const float* vrow = vpad + ((size_t)(b * V_C + vc) * QPH + 2 * oh) * QPW + 2 * ow;
        const float* ar = ab + vc * 16;
        #pragma unroll
        for (int kh = 0; kh < 4; ++kh)
            #pragma unroll
            for (int kw = 0; kw < 4; ++kw)
                s = fmaf(vrow[kh * QPW + kw], ar[kh * 4 + kw], s);
    }
    out[idx] = s;
}

extern "C" void kernel_launch(void* const* d_in, const int* in_sizes, int n_in,
                              void* d_out, int out_size, void* d_ws, size_t ws_size,
                              hipStream_t stream) {
    (void)in_sizes; (void)n_in; (void)out_size; (void)ws_size;
    const float* x  = (const float*)d_in[0];
    const float* Wq = (const float*)d_in[1];
    const float* bq = (const float*)d_in[2];
    const float* Wk = (const float*)d_in[3];
    const float* bk = (const float*)d_in[4];
    const float* Wv = (const float*)d_in[5];
    const float* bv = (const float*)d_in[6];
    float* out = (float*)d_out;

    // ws layout: [planes bf16][vpad f32][qpad bf16][D f32][a f32]
    char* p = (char*)d_ws;
    unsigned short* planes = (unsigned short*)p;        p += (size_t)PLANES_N * 2;
    float*          vpad   = (float*)p;                 p += (size_t)VPAD_N * 4;
    unsigned short* qpad   = (unsigned short*)p;        p += (size_t)QPAD1_N * 2;
    float*          D      = (float*)p;                 p += (size_t)D_N * 4;
    float*          a      = (float*)p;
    // total ~48 MiB

    kX<<<(PLANES_N + 255) / 256, 256, 0, stream>>>(x, planes);
    // zero vpad borders, qpad borders, D accumulators (contiguous region)
    hipMemsetAsync(vpad, 0,
                   (size_t)VPAD_N * 4 + (size_t)QPAD1_N * 2 + (size_t)D_N * 4, stream);
    kQV<<<BATCH * 7 * 10, 256, 0, stream>>>(planes, Wq, bq, Wv, bv, qpad, vpad);
    kC<<<14 * 16, 512, 0, stream>>>(planes, qpad, D);
    kE<<<BATCH * IN_C * V_C, 256, 0, stream>>>(D, Wk, bk, a);
    kO<<<(OUT_N + 255) / 256, 256, 0, stream>>>(vpad, a, out);
}

// Round 11
// 282.825 us; speedup vs baseline: 1.0667x; 1.0667x over previous
//
#include <hip/hip_runtime.h>
#include <hip/hip_bf16.h>

// Problem constants
#define BATCH 16
#define IN_C 3
#define Q_C 8
#define V_C 16
#define HH 224
#define WW 224
#define KK 7

// Padded layouts
#define XPH 230   // plane row = orig x row + 3
#define QPH 118
#define QPW 120

// Region sizes (elements)
#define PLANES_N (BATCH*7*IN_C*XPH*QPW)        // 9,273,600 bf16
#define VPAD_N   (BATCH*V_C*QPH*QPW)           // 3,624,960 f32
#define QPAD1_STRIDE (Q_C*QPH*QPW)             // 113,280 per (b,ic)
#define QPAD1_N  (BATCH*IN_C*QPAD1_STRIDE)     // 5,437,440 bf16 (single copy!)
#define D_N      (BATCH*IN_C*128*160)          // 983,040 f32
#define OUT_N    (BATCH*IN_C*58*58)

#define PSTR 137                               // ring plane stride in uint4 (8*17+1: banks +4 mod 32)
#define ONES_BASE (21*PSTR)

typedef __attribute__((ext_vector_type(8))) short bf16x8;
typedef __attribute__((ext_vector_type(4))) float f32x4;

static __device__ inline unsigned short f2b(float f) {
    __hip_bfloat16 h = __float2bfloat16(f);
    return *reinterpret_cast<unsigned short*>(&h);
}

// ---------------- Kernel X: dx-deinterleaved bf16 planes of x ----------------
__global__ __launch_bounds__(256) void kX(const float* __restrict__ x,
                                          unsigned short* __restrict__ planes) {
    int idx = blockIdx.x * 256 + threadIdx.x;
    if (idx >= PLANES_N) return;
    int k = idx % QPW;
    int t = idx / QPW;
    int row = t % XPH; t /= XPH;
    int ci = t % IN_C; t /= IN_C;
    int dx = t % 7;
    int b  = t / 7;
    int r = row - 3;
    int c = 2 * k + dx - 3;
    float val = 0.0f;
    if (r >= 0 && r < HH && c >= 0 && c < WW)
        val = x[((size_t)(b * IN_C + ci) * HH + r) * WW + c];
    planes[idx] = f2b(val);
}

// ---------------- Kernel QV: q conv + v conv, channel-groups looped in-block --
// Grid = (b, pb, half of channel range) = 224 blocks. Each block stages 20
// channels' weights in LDS and sweeps its x footprint (147 uint4/thread) FIVE
// times from L1/L2 (block working set 588 KB << 4 MB XCD L2) — R10 ran the 10
// groups as separate blocks round-robined across XCDs, re-pulling HBM 10x
// (FETCH 231 MB). Channels: 0..23 = q (ic,qc), 24..39 = v.
__global__ __launch_bounds__(256) void kQV(const unsigned short* __restrict__ planes,
                                           const float* __restrict__ Wq,
                                           const float* __restrict__ bq,
                                           const float* __restrict__ Wv,
                                           const float* __restrict__ bv,
                                           unsigned short* __restrict__ qpad,
                                           float* __restrict__ vpad) {
    int blk  = blockIdx.x;              // (b*7 + pb)*2 + half
    int half = blk & 1;
    int t2   = blk >> 1;
    int pb   = t2 % 7;
    int b    = t2 / 7;
    int tid  = threadIdx.x;

    __shared__ float wlds[20 * IN_C * KK * 8];  // [lc][ci][dy][dx pad 8]
    __shared__ float bsh[20];

    // stage 20 channels x 21 (ci,dy) rows
    for (int t = tid; t < 420; t += 256) {
        int lc = t / 21, rest = t % 21;
        int ch = half * 20 + lc;
        const float* wsrc = (ch < 24) ? (Wq + (size_t)ch * 147)
                                      : (Wv + (size_t)(ch - 24) * 147);
        #pragma unroll
        for (int dx = 0; dx < 7; ++dx) wlds[t * 8 + dx] = wsrc[rest * 7 + dx];
        wlds[t * 8 + 7] = 0.0f;
    }
    if (tid < 20) {
        int ch = half * 20 + tid;
        bsh[tid] = (ch < 24) ? bq[ch] : bv[ch - 24];
    }
    __syncthreads();

    int pos = pb * 256 + tid;
    if (pos >= 112 * 14) return;
    int y   = pos / 14;
    int seg = pos - y * 14;
    int row = y + 3, c0 = 8 * seg + 3;

    for (int g = 0; g < 5; ++g) {
        float kv[4][8];
        #pragma unroll
        for (int cc = 0; cc < 4; ++cc)
            #pragma unroll
            for (int j = 0; j < 8; ++j) kv[cc][j] = bsh[g * 4 + cc];

        for (int ci = 0; ci < IN_C; ++ci) {
            for (int dy = 0; dy < KK; ++dy) {
                int absrow = 2 * y + dy;
                float wv_[4][8];
                #pragma unroll
                for (int cc = 0; cc < 4; ++cc) {
                    const float* wbase = &wlds[(((g * 4 + cc) * IN_C + ci) * KK + dy) * 8];
                    *(float4*)&wv_[cc][0] = ((const float4*)wbase)[0];
                    *(float4*)&wv_[cc][4] = ((const float4*)wbase)[1];
                }
                #pragma unroll
                for (int dx = 0; dx < 7; ++dx) {
                    const unsigned short* src = planes
                        + (((size_t)(b * 7 + dx) * IN_C + ci) * XPH + absrow) * QPW + 8 * seg;
                    uint4 rv = *(const uint4*)src;
                    float xf[8];
                    xf[0] = __uint_as_float(rv.x << 16);
                    xf[1] = __uint_as_float(rv.x & 0xFFFF0000u);
                    xf[2] = __uint_as_float(rv.y << 16);
                    xf[3] = __uint_as_float(rv.y & 0xFFFF0000u);
                    xf[4] = __uint_as_float(rv.z << 16);
                    xf[5] = __uint_as_float(rv.z & 0xFFFF0000u);
                    xf[6] = __uint_as_float(rv.w << 16);
                    xf[7] = __uint_as_float(rv.w & 0xFFFF0000u);
                    #pragma unroll
                    for (int cc = 0; cc < 4; ++cc)
                        #pragma unroll
                        for (int j = 0; j < 8; ++j)
                            kv[cc][j] = fmaf(wv_[cc][dx], xf[j], kv[cc][j]);
                }
            }
        }

        #pragma unroll
        for (int cc = 0; cc < 4; ++cc) {
            int ch = half * 20 + g * 4 + cc;
            if (ch < 24) {
                int icq = ch >> 3, qc = ch & 7;
                unsigned short* bp = qpad
                    + ((size_t)(b * IN_C + icq) * Q_C + qc) * (QPH * QPW)
                    + (size_t)row * QPW + c0;
                bp[0] = f2b(kv[cc][0]);
                unsigned int* dp = (unsigned int*)(bp + 1);  // 16seg+8: dword-aligned
                dp[0] = (unsigned int)f2b(kv[cc][1]) | ((unsigned int)f2b(kv[cc][2]) << 16);
                dp[1] = (unsigned int)f2b(kv[cc][3]) | ((unsigned int)f2b(kv[cc][4]) << 16);
                dp[2] = (unsigned int)f2b(kv[cc][5]) | ((unsigned int)f2b(kv[cc][6]) << 16);
                bp[7] = f2b(kv[cc][7]);
            } else {
                int vc = ch - 24;
                float* op = vpad + (((size_t)(b * V_C + vc)) * QPH + row) * QPW + c0;
                #pragma unroll
                for (int j = 0; j < 8; ++j) op[j] = kv[cc][j];
            }
        }
    }
}

// ---------------- Kernel C: MFMA GEMM, ring-buffer B + single-copy A ---------
// Block = (b, yc). 512 thr / 8 waves, M=384 shared-B. A fragments from the
// single qpad copy via two aligned uint4 loads + dword selects. Ring plane
// stride PSTR=137 uint4 (+4 banks mod 32). Ones row K-tail zeroed (R9 bug).
__global__ __launch_bounds__(512, 1) void kC(const unsigned short* __restrict__ planes,
                                             const unsigned short* __restrict__ qpad,
                                             float* __restrict__ D) {
    int blk = blockIdx.x;
    int b  = blk & 15;
    int yc = blk >> 4;
    int tid = threadIdx.x;
    int w = tid >> 6, lane = tid & 63;
    int tt = lane & 15, kq = lane >> 4;
    int th = tt >> 2, tw = tt & 3;
    bool t1 = (tw & 1) != 0, t2 = (tw & 2) != 0;

    __shared__ uint4 smem[21 * PSTR + 17];   // 21 planes x (8-slot ring x 17) + ones

    // zero k-pad chunks 14,15 of every (plane,slot) row  [PSTR-correct]
    if (tid < 336) {
        int r = tid >> 1;                 // 0..167 = plane*8 + slot
        int p = r >> 3, slot = r & 7;
        smem[p * PSTR + slot * 17 + 14 + (tid & 1)] = uint4{0, 0, 0, 0};
    }
    // ones row: 1.0 for k<112 (chunks 0..13), 0 for the K-tail (chunks 14..16)
    if (tid >= 495) {
        int c = tid - 495;                // 0..16
        unsigned vv = (c < 14) ? 0x3F803F80u : 0u;
        uint4 o; o.x = o.y = o.z = o.w = vv;
        smem[ONES_BASE + c] = o;
    }
    // initial stage: slots 0..6 = plane rows 16*yc .. 16*yc+6
    #pragma unroll
    for (int i = 0; i < 5; ++i) {
        int c = tid + 512 * i;
        if (c < 21 * 7 * 14) {
            int p   = c / 98;
            int rem = c % 98;
            int rr  = rem / 14;
            int kc  = rem % 14;
            int ci = p / 7, dx = p % 7;
            const unsigned short* src = planes
                + (((size_t)(b * 7 + dx) * IN_C + ci) * XPH + 16 * yc + rr) * QPW + kc * 8;
            smem[p * PSTR + rr * 17 + kc] = *(const uint4*)src;
        }
    }

    // per-lane B-fragment LDS addressing constants
    int nbase[10], ndy[10], nmsk[10];
    #pragma unroll
    for (int nt = 0; nt < 10; ++nt) {
        int n = nt * 16 + tt;
        if (n < 147) {
            int ci = n / 49, rr = n % 49;
            nbase[nt] = (ci * 7 + (rr % 7)) * PSTR;
            ndy[nt]   = rr / 7;
            nmsk[nt]  = 7;
        } else {
            nbase[nt] = ONES_BASE; ndy[nt] = 0; nmsk[nt] = 0;
        }
    }

    // A row base per tile j: qpad[(b,ic)][qc] row (2*th)
    const unsigned short* abase[3];
    #pragma unroll
    for (int j = 0; j < 3; ++j) {
        int tile = w * 3 + j;
        int ic = tile >> 3, qc = tile & 7;
        abase[j] = qpad + ((size_t)(b * IN_C + ic) * Q_C + qc) * (QPH * QPW)
                 + (size_t)(2 * th) * QPW;
    }

    f32x4 acc[3][10];
    #pragma unroll
    for (int j = 0; j < 3; ++j)
        #pragma unroll
        for (int nt = 0; nt < 10; ++nt)
            acc[j][nt] = f32x4{0.f, 0.f, 0.f, 0.f};

    __syncthreads();

    for (int ry = 0; ry < 8; ++ry) {
        int yo = yc * 8 + ry;
        // prefetch next two plane rows (2*yo+7, 2*yo+8) into registers
        uint4 pv0, pv1; int pd0 = -1, pd1 = -1;
        if (ry < 7) {
            {
                int c = tid;
                int rn = c / 294, rem = c % 294;
                int p = rem / 14, kc = rem % 14;
                int ci = p / 7, dx = p % 7;
                int absrow = 16 * yc + 2 * ry + 7 + rn;
                pv0 = *(const uint4*)(planes
                    + (((size_t)(b * 7 + dx) * IN_C + ci) * XPH + absrow) * QPW + kc * 8);
                pd0 = p * PSTR + (absrow & 7) * 17 + kc;
            }
            int c = tid + 512;
            if (c < 588) {
                int rn = c / 294, rem = c % 294;
                int p = rem / 14, kc = rem % 14;
                int ci = p / 7, dx = p % 7;
                int absrow = 16 * yc + 2 * ry + 7 + rn;
                pv1 = *(const uint4*)(planes
                    + (((size_t)(b * 7 + dx) * IN_C + ci) * XPH + absrow) * QPW + kc * 8);
                pd1 = p * PSTR + (absrow & 7) * 17 + kc;
            }
        }
        int ry2 = 2 * ry;
        #pragma unroll
        for (int s = 0; s < 4; ++s) {
            int k = 32 * s + kq * 8;
            int xs = (k < 112) ? k : 96;       // clamped; multiplies B-zeros
            bf16x8 af[3];
            #pragma unroll
            for (int j = 0; j < 3; ++j) {
                const unsigned int* dp =
                    (const unsigned int*)(abase[j] + (size_t)yo * QPW) + (xs >> 1);
                uint4 U0 = *(const uint4*)dp;
                uint4 U1 = *(const uint4*)(dp + 4);
                // fragment dword r = X[tw + r], X = concat(U0,U1)
                unsigned int f0 = t2 ? (t1 ? U0.w : U0.z) : (t1 ? U0.y : U0.x);
                unsigned int f1 = t2 ? (t1 ? U1.x : U0.w) : (t1 ? U0.z : U0.y);
                unsigned int f2 = t2 ? (t1 ? U1.y : U1.x) : (t1 ? U0.w : U0.z);
                unsigned int f3 = t2 ? (t1 ? U1.z : U1.y) : (t1 ? U1.x : U0.w);
                uint4 fr{f0, f1, f2, f3};
                af[j] = __builtin_bit_cast(bf16x8, fr);
            }
            #pragma unroll
            for (int nt = 0; nt < 10; ++nt) {
                bf16x8 bf = __builtin_bit_cast(bf16x8,
                    smem[nbase[nt] + ((ry2 + ndy[nt]) & nmsk[nt]) * 17 + 4 * s + kq]);
                #pragma unroll
                for (int j = 0; j < 3; ++j)
                    acc[j][nt] = __builtin_amdgcn_mfma_f32_16x16x32_bf16(af[j], bf, acc[j][nt], 0, 0, 0);
            }
        }
        __syncthreads();                        // all reads of ring done
        if (pd0 >= 0) smem[pd0] = pv0;
        if (pd1 >= 0) smem[pd1] = pv1;
        __syncthreads();                        // new rows visible
    }

    // epilogue: atomics into D. C/D layout: col = lane&15, row = (lane>>4)*4+reg
    int rowb = kq * 4;
    #pragma unroll
    for (int j = 0; j < 3; ++j) {
        int tile = w * 3 + j;
        int ic = tile >> 3, qc = tile & 7;
        float* Dbi = D + (size_t)(b * IN_C + ic) * (128 * 160);
        int m = qc * 16 + rowb;
        #pragma unroll
        for (int nt = 0; nt < 10; ++nt) {
            int n = nt * 16 + tt;
            if (n < 148) {
                #pragma unroll
                for (int r = 0; r < 4; ++r)
                    atomicAdd(&Dbi[(size_t)(m + r) * 160 + n], acc[j][nt][r]);
            }
        }
    }
}

// ---------------- Kernel E: a[v,t] = sum_{qc,r} Wk*D + sum_qc bk*D[.,147] ----
__global__ __launch_bounds__(256) void kE(const float* __restrict__ D,
                                          const float* __restrict__ Wk,
                                          const float* __restrict__ bk,
                                          float* __restrict__ a_out) {
    int blk = blockIdx.x;              // (b*3+ic)*16 + v
    int bi = blk >> 4;
    int v  = blk & 15;
    int ic = bi % IN_C;
    int tid = threadIdx.x;
    int t  = tid >> 4;
    int rl = tid & 15;
    const float* Dbi = D + (size_t)bi * (128 * 160);
    const float* WkI = Wk + (size_t)(ic * V_C + v) * (Q_C * 147);
    const float* bkI = bk + (ic * V_C + v) * Q_C;
    float s = 0.0f;
    for (int qc = 0; qc < Q_C; ++qc) {
        const float* drow = Dbi + (qc * 16 + t) * 160;
        const float* wrow = WkI + qc * 147;
        #pragma unroll
        for (int j = 0; j < 10; ++j) {
            int r = rl + 16 * j;
            if (r < 147) s = fmaf(wrow[r], drow[r], s);
        }
        if (rl == 0) s = fmaf(bkI[qc], drow[147], s);
    }
    s += __shfl_down(s, 8, 64);
    s += __shfl_down(s, 4, 64);
    s += __shfl_down(s, 2, 64);
    s += __shfl_down(s, 1, 64);
    if (rl == 0) a_out[(size_t)blk * 16 + t] = s;
}

// ---------------- Kernel O: final dynamic conv -> out ----------------
__global__ __launch_bounds__(256) void kO(const float* __restrict__ vpad,
                                          const float* __restrict__ a,
                                          float* __restrict__ out) {
    int idx = blockIdx.x * 256 + threadIdx.x;
    if (idx >= OUT_N) return;
    int ow = idx % 58;
    int t = idx / 58;
    int oh = t % 58; t /= 58;
    int ic = t % IN_C;
    int b  = t / IN_C;
    const float* ab = a + (size_t)(b * IN_C + ic) * (V_C * 16);
    float s = 0.0f;
    for (int vc = 0; vc < V_C; ++vc) {
        const float* vrow = vpad + ((size_t)(b * V_C + vc) * QPH + 2 * oh) * QPW + 2 * ow;
        const float* ar = ab + vc * 16;
        #pragma unroll
        for (int kh = 0; kh < 4; ++kh)
            #pragma unroll
            for (int kw = 0; kw < 4; ++kw)
                s = fmaf(vrow[kh * QPW + kw], ar[kh * 4 + kw], s);
    }
    out[idx] = s;
}

extern "C" void kernel_launch(void* const* d_in, const int* in_sizes, int n_in,
                              void* d_out, int out_size, void* d_ws, size_t ws_size,
                              hipStream_t stream) {
    (void)in_sizes; (void)n_in; (void)out_size; (void)ws_size;
    const float* x  = (const float*)d_in[0];
    const float* Wq = (const float*)d_in[1];
    const float* bq = (const float*)d_in[2];
    const float* Wk = (const float*)d_in[3];
    const float* bk = (const float*)d_in[4];
    const float* Wv = (const float*)d_in[5];
    const float* bv = (const float*)d_in[6];
    float* out = (float*)d_out;

    // ws layout: [planes bf16][vpad f32][qpad bf16][D f32][a f32]
    char* p = (char*)d_ws;
    unsigned short* planes = (unsigned short*)p;        p += (size_t)PLANES_N * 2;
    float*          vpad   = (float*)p;                 p += (size_t)VPAD_N * 4;
    unsigned short* qpad   = (unsigned short*)p;        p += (size_t)QPAD1_N * 2;
    float*          D      = (float*)p;                 p += (size_t)D_N * 4;
    float*          a      = (float*)p;
    // total ~48 MiB

    kX<<<(PLANES_N + 255) / 256, 256, 0, stream>>>(x, planes);
    // zero vpad borders, qpad borders, D accumulators (contiguous region)
    hipMemsetAsync(vpad, 0,
                   (size_t)VPAD_N * 4 + (size_t)QPAD1_N * 2 + (size_t)D_N * 4, stream);
    kQV<<<BATCH * 7 * 2, 256, 0, stream>>>(planes, Wq, bq, Wv, bv, qpad, vpad);
    kC<<<14 * 16, 512, 0, stream>>>(planes, qpad, D);
    kE<<<BATCH * IN_C * V_C, 256, 0, stream>>>(D, Wk, bk, a);
    kO<<<(OUT_N + 255) / 256, 256, 0, stream>>>(vpad, a, out);
}